// Round 6
// baseline (2922.785 us; speedup 1.0000x reference)
//
#include <hip/hip_runtime.h>
#include <hip/hip_bf16.h>
#include <stdint.h>

// ACT (adaptive computation time) on MI355X.
// R11: R10 post-mortem — coop launch fails under graph capture (timed run
// was the fallback); the rocprof'd mega-kernel ran 4550us at MfmaUtil 9%,
// FETCH 2x: grid.sync on 8 non-coherent XCD L2s = per-wave threadfence ->
// L2 writeback storms that also evict the B strips. Persistent direction
// dead. R11 instead removes real work and restores the best-measured GEMM:
// (a) ponder no longer reads state: gemm2's epilogue computes deterministic
//     per-strip partials pdot8[pos][8] of dot(h,Wp) (fixed slots, no
//     atomics); k_prep seeds pdot8 from state0 and edot[t]=dot(emb_t,Wp).
//     k_plite = 64-block scalar sigmoid+halting kernel (~3us, tails free).
//     Rounding: dot re-association, +-2^-22 on p — same perturbation class
//     as the bf16x3 GEMM already imposes vs jax; seed tolerates with margin.
// (b) GEMMs back to R5's single-buffered 2-barrier loop (bit-identical
//     accumulation kt->pb->pa->mt->nt), A gathered from stateF via ridx,
//     emb added from global (L1-resident): LDS exactly 40960 B +
//     __launch_bounds__(256,4) -> 4 blocks/CU (was 3), more barrier groups.

#define THR 0.99f
typedef float4 f4;
typedef __attribute__((ext_vector_type(8))) short short8;
typedef __attribute__((ext_vector_type(4))) float f32x4;

__device__ __forceinline__ int detect_bf(const void* mask) {
  return (((const unsigned int*)mask)[0] == 0x3F803F80u) ? 1 : 0;
}

__device__ __forceinline__ float ld_in(const void* p, long i, int bf) {
  if (bf) {
    unsigned short u = ((const unsigned short*)p)[i];
    return __uint_as_float(((unsigned int)u) << 16);
  }
  return ((const float*)p)[i];
}
__device__ __forceinline__ f4 ld4(const float* p) { return *(const f4*)p; }

// truncation 3-way bf16 split: x ~= h + m + l, |err| <= 2^-24|x|
__device__ __forceinline__ void split3(float x, unsigned short& h,
                                       unsigned short& m, unsigned short& l) {
  unsigned u = __float_as_uint(x);
  h = (unsigned short)(u >> 16);
  float fh = __uint_as_float(u & 0xFFFF0000u);
  float r = x - fh;  // exact
  unsigned v = __float_as_uint(r);
  m = (unsigned short)(v >> 16);
  float fm = __uint_as_float(v & 0xFFFF0000u);
  l = (unsigned short)(__float_as_uint(r - fm) >> 16);
}

__device__ __forceinline__ void gld16(const void* g, void* l) {
  __builtin_amdgcn_global_load_lds(
      (const __attribute__((address_space(1))) void*)g,
      (__attribute__((address_space(3))) void*)l, 16, 0, 0);
}

#define MFMA16 __builtin_amdgcn_mfma_f32_16x16x32_bf16

// ---------- prep: small param conversion + sdot0 + edot -------------------
__global__ __launch_bounds__(256) void k_prep(
    const void* mask, const void* state, const void* emb, const void* Wp,
    const void* bp, const void* b1, const void* b2, float* embF, float* WpF,
    float* bpF, float* b1F, float* b2F, float* pdot8, float* edot) {
  int bf = detect_bf(mask);
  int tid = threadIdx.x;
  long gt = (long)blockIdx.x * 256 + tid;
  long gs = (long)gridDim.x * 256;
  for (long i = gt; i < 5632; i += gs) embF[i] = ld_in(emb, i, bf);
  for (long i = gt; i < 512; i += gs) {
    WpF[i] = ld_in(Wp, i, bf);
    b2F[i] = ld_in(b2, i, bf);
  }
  for (long i = gt; i < 2048; i += gs) b1F[i] = ld_in(b1, i, bf);
  if (gt == 0) bpF[0] = ld_in(bp, 0, bf);
  int lane = tid & 63, wv = tid >> 6;
  int d = lane * 8;
  float wp[8];
#pragma unroll
  for (int j = 0; j < 8; ++j) wp[j] = ld_in(Wp, d + j, bf);
  // sdot0: 256 blocks x 4 waves x 16 positions
#pragma unroll 1
  for (int i = 0; i < 16; ++i) {
    int pos = (blockIdx.x * 4 + wv) * 16 + i;
    float sv[8];
#pragma unroll
    for (int j = 0; j < 8; ++j) sv[j] = ld_in(state, (long)pos * 512 + d + j, bf);
    float acc = sv[0] * wp[0];
#pragma unroll
    for (int j = 1; j < 8; ++j) acc = fmaf(sv[j], wp[j], acc);
#pragma unroll
    for (int off = 32; off > 0; off >>= 1) acc += __shfl_xor(acc, off, 64);
    if (lane == 0) pdot8[(long)pos * 8] = acc;
    if (lane >= 1 && lane < 8) pdot8[(long)pos * 8 + lane] = 0.f;
  }
  // edot[t] = dot(emb_t, Wp): blocks 0..10, wave 0
  if (blockIdx.x < 11 && wv == 0) {
    int t = blockIdx.x;
    float ev[8];
#pragma unroll
    for (int j = 0; j < 8; ++j) ev[j] = ld_in(emb, (long)t * 512 + d + j, bf);
    float acc = ev[0] * wp[0];
#pragma unroll
    for (int j = 1; j < 8; ++j) acc = fmaf(ev[j], wp[j], acc);
#pragma unroll
    for (int off = 32; off > 0; off >>= 1) acc += __shfl_xor(acc, off, 64);
    if (lane == 0) edot[t] = acc;
  }
}

// ---------- big conversions + weight transpose/split + zero init ----------
__global__ void k_init(const void* state, const void* W1, const void* W2,
                       const void* mask, float* stateF, unsigned short* w1t,
                       unsigned short* w2t, float* maskF, float* prevF,
                       float* hp, float* rem, float* nup, int* counts) {
  int bf = detect_bf(mask);
  long t = (long)blockIdx.x * blockDim.x + threadIdx.x;
  long st = (long)gridDim.x * blockDim.x;
  for (long i = t; i < 8388608L; i += st) {
    stateF[i] = ld_in(state, i, bf);
    prevF[i] = 0.f;
  }
  // W1 [512][2048] -> W1T planes [2048][512] bf16 x3 (plane stride 1048576)
  for (long i = t; i < 1048576L; i += st) {
    float v = ld_in(W1, i, bf);
    long n = i & 2047, k = i >> 11;
    unsigned short h, m, l;
    split3(v, h, m, l);
    long o = n * 512 + k;
    w1t[o] = h;
    w1t[1048576L + o] = m;
    w1t[2097152L + o] = l;
  }
  // W2 [2048][512] -> W2T planes [512][2048] bf16 x3
  for (long i = t; i < 1048576L; i += st) {
    float v = ld_in(W2, i, bf);
    long k = i >> 9, n = i & 511;
    unsigned short h, m, l;
    split3(v, h, m, l);
    long o = n * 2048 + k;
    w2t[o] = h;
    w2t[1048576L + o] = m;
    w2t[2097152L + o] = l;
  }
  for (long i = t; i < 16384L; i += st) {
    maskF[i] = ld_in(mask, i, bf);
    hp[i] = 0.f;
    rem[i] = 0.f;
    nup[i] = 0.f;
  }
  if (t < 11) counts[t] = 0;
}

// ---------- ponder-lite: 1 thread / position, no state read ---------------
__global__ __launch_bounds__(256) void k_plite(
    const float* __restrict__ pdot8, const float* __restrict__ edot,
    const float* __restrict__ bpF, float* hp, float* rem, float* nup,
    float* uw, int* __restrict__ count, int* __restrict__ ridx, int t) {
  int pos = blockIdx.x * 256 + threadIdx.x;
  float hpv = hp[pos];
  if (hpv >= 1.0f) return;  // halted forever
  const float* pd = pdot8 + (long)pos * 8;
  float s8 = pd[0];
#pragma unroll
  for (int k = 1; k < 8; ++k) s8 += pd[k];
  float p = 1.0f / (1.0f + expf(-(s8 + edot[t] + bpF[0])));
  float q = hpv + p;
  float nh = (q > THR) ? 1.0f : 0.0f;
  float st2 = (q <= THR) ? 1.0f : 0.0f;
  float hpn = hpv + p * st2;
  float remn = rem[pos] + nh * (1.0f - hpn);
  hpn = hpn + nh * remn;
  nup[pos] = nup[pos] + st2 + nh;
  uw[pos] = p * st2 + nh * remn;
  hp[pos] = hpn;
  rem[pos] = remn;
  int idx = atomicAdd(count, 1);
  ridx[idx] = pos;
}

// LDS (both GEMMs, dynamic 40960 B -> 4 blocks/CU):
//   Au fp32 [4 q][2 h][128 rows][4] = 16384 B at 0
//   Bs bf16 [3 p][4 q][128 rows][8] = 24576 B at 16384
// Stage region = 1KB (64 lanes x 16B); R5 layouts, 0 bank conflicts verified.

// ---------- GEMM1: U = relu((state[ridx]+emb) * W1 + b1) -> U fp32 --------
// A: stateF gathered via ridx; emb added in-register from global (L1-res).
// B: W1T planes; K=512 (16 kt), N=2048; XCD-pinned swizzle (x = bid&7).
__global__ __launch_bounds__(256, 4) void k_gemm1(
    const float* __restrict__ stateF, const float* __restrict__ embT,
    const unsigned short* __restrict__ w1t, const float* __restrict__ b1F,
    const int* __restrict__ count, const int* __restrict__ ridx,
    float* __restrict__ U, int c0, int mc) {
  int Ma = *count;
  int mEnd = c0 + mc;
  if (Ma < mEnd) mEnd = Ma;
  int f = blockIdx.x;
  int x = f & 7, s = f >> 3;
  int n0 = (x * 2 + (s & 1)) * 128;
  int m0 = c0 + (s >> 1) * 128;
  if (m0 >= mEnd) return;
  extern __shared__ __align__(16) char lds[];
  float* Au = (float*)lds;
  unsigned short* Bs = (unsigned short*)(lds + 16384);
  int tid = threadIdx.x;
  int lane = tid & 63, wv = tid >> 6;
  int quad = lane >> 4, ln15 = lane & 15;
  int wm = (wv >> 1) << 6, wn = (wv & 1) << 6;
  int rr0 = m0 + lane;
  if (rr0 >= mEnd) rr0 = mEnd - 1;
  int rr1 = m0 + 64 + lane;
  if (rr1 >= mEnd) rr1 = mEnd - 1;
  long pos0 = ridx[rr0], pos1 = ridx[rr1];
  f32x4 acc[4][4];
#pragma unroll
  for (int i = 0; i < 4; i++)
#pragma unroll
    for (int j = 0; j < 4; j++) acc[i][j] = (f32x4)0.f;
#pragma unroll 1
  for (int kt = 0; kt < 16; ++kt) {
    __syncthreads();
#pragma unroll
    for (int i = 0; i < 4; ++i) {  // A staging fp32 gather
      int g = wv + 4 * i;
      int q = g >> 2, h = (g >> 1) & 1, rh = g & 1;
      long po = rh ? pos1 : pos0;
      gld16(stateF + po * 512 + kt * 32 + q * 8 + h * 4,
            Au + ((q * 2 + h) * 128 + rh * 64) * 4);
    }
#pragma unroll
    for (int i = 0; i < 6; ++i) {  // B staging
      int g = wv + 4 * i;
      int p = g >> 3, q = (g >> 1) & 3, rh = g & 1;
      long n = n0 + rh * 64 + lane;
      gld16(w1t + (long)p * 1048576L + n * 512 + kt * 32 + q * 8,
            Bs + ((p * 4 + q) * 128 + rh * 64) * 8);
    }
    __syncthreads();
    float es[8];
    {
      f4 e0 = ld4(embT + kt * 32 + quad * 8);
      f4 e1 = ld4(embT + kt * 32 + quad * 8 + 4);
      es[0] = e0.x; es[1] = e0.y; es[2] = e0.z; es[3] = e0.w;
      es[4] = e1.x; es[5] = e1.y; es[6] = e1.z; es[7] = e1.w;
    }
    short8 af[3][4];
#pragma unroll
    for (int mt = 0; mt < 4; ++mt) {
      int row = wm + mt * 16 + ln15;
      f4 x0 = *(const f4*)(Au + ((quad * 2 + 0) * 128 + row) * 4);
      f4 x1 = *(const f4*)(Au + ((quad * 2 + 1) * 128 + row) * 4);
      float xs[8];
      xs[0] = x0.x + es[0]; xs[1] = x0.y + es[1];
      xs[2] = x0.z + es[2]; xs[3] = x0.w + es[3];
      xs[4] = x1.x + es[4]; xs[5] = x1.y + es[5];
      xs[6] = x1.z + es[6]; xs[7] = x1.w + es[7];
#pragma unroll
      for (int j = 0; j < 8; ++j) {
        unsigned short h_, m_, l_;
        split3(xs[j], h_, m_, l_);
        ((unsigned short*)&af[0][mt])[j] = h_;
        ((unsigned short*)&af[1][mt])[j] = m_;
        ((unsigned short*)&af[2][mt])[j] = l_;
      }
    }
    const unsigned short* bs = Bs + quad * 1024 + (wn + ln15) * 8;
#pragma unroll
    for (int pb = 0; pb < 3; ++pb) {
      short8 bfr[4];
#pragma unroll
      for (int nt = 0; nt < 4; ++nt)
        bfr[nt] = *(const short8*)(bs + pb * 4096 + nt * 128);
      int npa = (pb == 0) ? 3 : ((pb == 1) ? 2 : 1);
      for (int pa = 0; pa < npa; ++pa)
#pragma unroll
        for (int mt = 0; mt < 4; ++mt)
#pragma unroll
          for (int nt = 0; nt < 4; ++nt)
            acc[mt][nt] = MFMA16(af[pa][mt], bfr[nt], acc[mt][nt], 0, 0, 0);
    }
  }
#pragma unroll
  for (int mt = 0; mt < 4; ++mt)
#pragma unroll
    for (int reg = 0; reg < 4; ++reg) {
      int r = m0 + wm + mt * 16 + quad * 4 + reg;
      if (r < mEnd) {
        long lr = r - c0;
#pragma unroll
        for (int nt = 0; nt < 4; ++nt) {
          int n = n0 + wn + nt * 16 + ln15;
          U[lr * 2048 + n] = fmaxf(acc[mt][nt][reg] + b1F[n], 0.f);
        }
      }
    }
}

// ---------- GEMM2: h = U*W2 + b2; state=h*mask; prev += h*uw; pdot8 -------
// A: U fp32 local rows; B: W2T planes; K=2048 (64 kt), N=512.
// Epilogue also writes deterministic per-strip partials of dot(h, Wp):
// pdot8[pos*8 + (n0>>7)*2 + (wv&1)] (8 fixed slots per row, no atomics).
__global__ __launch_bounds__(256, 4) void k_gemm2(
    const float* __restrict__ U, const unsigned short* __restrict__ w2t,
    const float* __restrict__ b2F, const int* __restrict__ count,
    const int* __restrict__ ridx, const float* __restrict__ maskF,
    const float* __restrict__ uwF, const float* __restrict__ WpF,
    float* __restrict__ stateF, float* __restrict__ prevF,
    float* __restrict__ pdot8, int c0, int mc) {
  int Ma = *count;
  int mEnd = c0 + mc;
  if (Ma < mEnd) mEnd = Ma;
  int f = blockIdx.x;
  int x = f & 7, s = f >> 3;
  int n0 = (x >> 1) * 128;
  int m0 = c0 + (s * 2 + (x & 1)) * 128;
  if (m0 >= mEnd) return;
  extern __shared__ __align__(16) char lds[];
  float* Au = (float*)lds;
  unsigned short* Bs = (unsigned short*)(lds + 16384);
  int tid = threadIdx.x;
  int lane = tid & 63, wv = tid >> 6;
  int quad = lane >> 4, ln15 = lane & 15;
  int wm = (wv >> 1) << 6, wn = (wv & 1) << 6;
  long lr0 = (long)(m0 - c0) + lane;
  long lr1 = lr0 + 64;
  f32x4 acc[4][4];
#pragma unroll
  for (int i = 0; i < 4; i++)
#pragma unroll
    for (int j = 0; j < 4; j++) acc[i][j] = (f32x4)0.f;
#pragma unroll 1
  for (int kt = 0; kt < 64; ++kt) {
    __syncthreads();
#pragma unroll
    for (int i = 0; i < 4; ++i) {  // A staging fp32
      int g = wv + 4 * i;
      int q = g >> 2, h = (g >> 1) & 1, rh = g & 1;
      long lr = rh ? lr1 : lr0;
      gld16(U + lr * 2048 + kt * 32 + q * 8 + h * 4,
            Au + ((q * 2 + h) * 128 + rh * 64) * 4);
    }
#pragma unroll
    for (int i = 0; i < 6; ++i) {  // B staging
      int g = wv + 4 * i;
      int p = g >> 3, q = (g >> 1) & 3, rh = g & 1;
      long n = n0 + rh * 64 + lane;
      gld16(w2t + (long)p * 1048576L + n * 2048 + kt * 32 + q * 8,
            Bs + ((p * 4 + q) * 128 + rh * 64) * 8);
    }
    __syncthreads();
    short8 af[3][4];
#pragma unroll
    for (int mt = 0; mt < 4; ++mt) {
      int row = wm + mt * 16 + ln15;
      f4 x0 = *(const f4*)(Au + ((quad * 2 + 0) * 128 + row) * 4);
      f4 x1 = *(const f4*)(Au + ((quad * 2 + 1) * 128 + row) * 4);
      float xs[8];
      xs[0] = x0.x; xs[1] = x0.y; xs[2] = x0.z; xs[3] = x0.w;
      xs[4] = x1.x; xs[5] = x1.y; xs[6] = x1.z; xs[7] = x1.w;
#pragma unroll
      for (int j = 0; j < 8; ++j) {
        unsigned short h_, m_, l_;
        split3(xs[j], h_, m_, l_);
        ((unsigned short*)&af[0][mt])[j] = h_;
        ((unsigned short*)&af[1][mt])[j] = m_;
        ((unsigned short*)&af[2][mt])[j] = l_;
      }
    }
    const unsigned short* bs = Bs + quad * 1024 + (wn + ln15) * 8;
#pragma unroll
    for (int pb = 0; pb < 3; ++pb) {
      short8 bfr[4];
#pragma unroll
      for (int nt = 0; nt < 4; ++nt)
        bfr[nt] = *(const short8*)(bs + pb * 4096 + nt * 128);
      int npa = (pb == 0) ? 3 : ((pb == 1) ? 2 : 1);
      for (int pa = 0; pa < npa; ++pa)
#pragma unroll
        for (int mt = 0; mt < 4; ++mt)
#pragma unroll
          for (int nt = 0; nt < 4; ++nt)
            acc[mt][nt] = MFMA16(af[pa][mt], bfr[nt], acc[mt][nt], 0, 0, 0);
    }
  }
#pragma unroll
  for (int mt = 0; mt < 4; ++mt)
#pragma unroll
    for (int reg = 0; reg < 4; ++reg) {
      int r = m0 + wm + mt * 16 + quad * 4 + reg;
      // r is uniform across the 16 ln15 lanes of each quad-group, so the
      // shfl_xor reduction below is exec-uniform within its group.
      if (r < mEnd) {
        long pos = (long)ridx[r];
        float mk = maskF[pos];
        float uv = uwF[pos];
        float pd = 0.f;
#pragma unroll
        for (int nt = 0; nt < 4; ++nt) {
          int n = n0 + wn + nt * 16 + ln15;
          float h = (acc[mt][nt][reg] + b2F[n]) * mk;
          long off = pos * 512 + n;
          stateF[off] = h;
          prevF[off] = fmaf(h, uv, prevF[off]);
          pd = fmaf(h, WpF[n], pd);
        }
        pd += __shfl_xor(pd, 1, 64);
        pd += __shfl_xor(pd, 2, 64);
        pd += __shfl_xor(pd, 4, 64);
        pd += __shfl_xor(pd, 8, 64);
        if (ln15 == 0)
          pdot8[pos * 8 + (long)((n0 >> 7) * 2 + (wv & 1))] = pd;
      }
    }
}

// ---------- final: concat outputs, cast per detected dtype ----------
__global__ void k_final(const float* prevF, const float* nupF,
                        const float* remF, void* out, const void* mask) {
  int bf = detect_bf(mask);
  long gt = (long)blockIdx.x * 256 + threadIdx.x;
  long gs = (long)gridDim.x * 256;
  for (long i = gt; i < 8421376L; i += gs) {
    float v;
    if (i < 8388608L) v = prevF[i];
    else if (i < 8404992L) v = nupF[i - 8388608L];
    else v = remF[i - 8404992L];
    if (bf) ((__hip_bfloat16*)out)[i] = __float2bfloat16(v);
    else ((float*)out)[i] = v;
  }
}

extern "C" void kernel_launch(void* const* d_in, const int* in_sizes, int n_in,
                              void* d_out, int out_size, void* d_ws,
                              size_t ws_size, hipStream_t stream) {
  const void* state = d_in[0];
  const void* mask = d_in[1];
  const void* emb = d_in[2];
  const void* Wp = d_in[3];
  const void* bp = d_in[4];
  const void* W1 = d_in[5];
  const void* b1 = d_in[6];
  const void* W2 = d_in[7];
  const void* b2 = d_in[8];
  char* w = (char*)d_ws;
  float* stateF = (float*)(w + 0L);
  float* prevF = (float*)(w + 33554432L);
  unsigned short* w1t = (unsigned short*)(w + 67108864L);  // 3 x 2 MB
  unsigned short* w2t = (unsigned short*)(w + 73400320L);  // 3 x 2 MB
  float* maskF = (float*)(w + 79691776L);
  float* hp = (float*)(w + 79757312L);
  float* rem = (float*)(w + 79822848L);
  float* nup = (float*)(w + 79888384L);
  float* uwf = (float*)(w + 79953920L);
  float* embF = (float*)(w + 80019456L);
  float* WpF = (float*)(w + 80052224L);
  float* b1F = (float*)(w + 80056320L);
  float* b2F = (float*)(w + 80064512L);
  float* bpF = (float*)(w + 80068608L);
  int* counts = (int*)(w + 80069120L);    // 11 ints
  float* edot = (float*)(w + 80069632L);  // 11 floats
  int* ridx = (int*)(w + 80070144L);      // 11 x 16384 x 4 B
  float* pdot8 = (float*)(w + 80791040L); // 16384 x 8 fp32 = 512 KB
  float* U = (float*)(w + 81315328L);     // fp32 [Mc][2048]
  long ub = (long)ws_size - 81315328L;
  long rows = ub / 8192L;
  long McL = rows & ~255L;  // multiple of 256 so T=mc/128 stays even
  if (McL > 16384L) McL = 16384L;
  if (McL < 256L) McL = 256L;
  int Mc = (int)McL;
  int nCh = (16384 + Mc - 1) / Mc;

  k_prep<<<256, 256, 0, stream>>>(mask, state, emb, Wp, bp, b1, b2, embF, WpF,
                                  bpF, b1F, b2F, pdot8, edot);
  k_init<<<2048, 256, 0, stream>>>(state, W1, W2, mask, stateF, w1t, w2t,
                                   maskF, prevF, hp, rem, nup, counts);
  for (int t = 0; t <= 10; t++) {
    k_plite<<<64, 256, 0, stream>>>(pdot8, edot, bpF, hp, rem, nup, uwf,
                                    counts + t, ridx + (long)t * 16384, t);
    for (int c = 0; c < nCh; c++) {
      int c0 = c * Mc;
      int mc = 16384 - c0;
      if (mc > Mc) mc = Mc;
      int T = mc / 128;  // even (Mc multiple of 256, 16384 multiple of 256)
      k_gemm1<<<T * 16, 256, 40960, stream>>>(stateF, embF + t * 512, w1t, b1F,
                                              counts + t,
                                              ridx + (long)t * 16384, U, c0,
                                              mc);
      k_gemm2<<<T * 4, 256, 40960, stream>>>(U, w2t, b2F, counts + t,
                                             ridx + (long)t * 16384, maskF,
                                             uwf, WpF, stateF, prevF, pdot8,
                                             c0, mc);
    }
  }
  k_final<<<2048, 256, 0, stream>>>(prevF, nup, rem, d_out, mask);
}

// Round 7
// 1681.248 us; speedup vs baseline: 1.7385x; 1.7385x over previous
//
#include <hip/hip_runtime.h>
#include <hip/hip_bf16.h>
#include <stdint.h>

// ACT (adaptive computation time) on MI355X.
// R12: R11 minus the register poison. R11 post-mortem: __launch_bounds__
// (256,4) forced VGPR=64 < the 64-reg accumulator + 48-reg af + 16-reg bfr
// live set -> accumulators spilled to scratch (k_gemm2 230->512us, FETCH
// 362MB, WRITE 151MB vs 67 ideal = scratch round-trips). Revert to plain
// __launch_bounds__(256) (R5 regime, VGPR 84-96, zero spill); 40960 B LDS
// already permits 4 blocks/CU at VGPR<=128 (m69 occupancy steps) without
// forcing. Keep R11's validated wins: ponder collapsed to k_plite (64-block
// scalar kernel; pdot8 per-strip partials written deterministically by
// gemm2's epilogue, seeded by k_prep; absmax unchanged = re-association
// tolerated), emb added in-register in gemm1, grid-strided k_final.
// GEMM core = R5's single-buffered 2-barrier loop, accumulation order
// kt->pb->pa->mt->nt, bit-identical to the 1991us baseline.

#define THR 0.99f
typedef float4 f4;
typedef __attribute__((ext_vector_type(8))) short short8;
typedef __attribute__((ext_vector_type(4))) float f32x4;

__device__ __forceinline__ int detect_bf(const void* mask) {
  return (((const unsigned int*)mask)[0] == 0x3F803F80u) ? 1 : 0;
}

__device__ __forceinline__ float ld_in(const void* p, long i, int bf) {
  if (bf) {
    unsigned short u = ((const unsigned short*)p)[i];
    return __uint_as_float(((unsigned int)u) << 16);
  }
  return ((const float*)p)[i];
}
__device__ __forceinline__ f4 ld4(const float* p) { return *(const f4*)p; }

// truncation 3-way bf16 split: x ~= h + m + l, |err| <= 2^-24|x|
__device__ __forceinline__ void split3(float x, unsigned short& h,
                                       unsigned short& m, unsigned short& l) {
  unsigned u = __float_as_uint(x);
  h = (unsigned short)(u >> 16);
  float fh = __uint_as_float(u & 0xFFFF0000u);
  float r = x - fh;  // exact
  unsigned v = __float_as_uint(r);
  m = (unsigned short)(v >> 16);
  float fm = __uint_as_float(v & 0xFFFF0000u);
  l = (unsigned short)(__float_as_uint(r - fm) >> 16);
}

__device__ __forceinline__ void gld16(const void* g, void* l) {
  __builtin_amdgcn_global_load_lds(
      (const __attribute__((address_space(1))) void*)g,
      (__attribute__((address_space(3))) void*)l, 16, 0, 0);
}

#define MFMA16 __builtin_amdgcn_mfma_f32_16x16x32_bf16

// ---------- prep: small param conversion + sdot0 + edot -------------------
__global__ __launch_bounds__(256) void k_prep(
    const void* mask, const void* state, const void* emb, const void* Wp,
    const void* bp, const void* b1, const void* b2, float* embF, float* WpF,
    float* bpF, float* b1F, float* b2F, float* pdot8, float* edot) {
  int bf = detect_bf(mask);
  int tid = threadIdx.x;
  long gt = (long)blockIdx.x * 256 + tid;
  long gs = (long)gridDim.x * 256;
  for (long i = gt; i < 5632; i += gs) embF[i] = ld_in(emb, i, bf);
  for (long i = gt; i < 512; i += gs) {
    WpF[i] = ld_in(Wp, i, bf);
    b2F[i] = ld_in(b2, i, bf);
  }
  for (long i = gt; i < 2048; i += gs) b1F[i] = ld_in(b1, i, bf);
  if (gt == 0) bpF[0] = ld_in(bp, 0, bf);
  int lane = tid & 63, wv = tid >> 6;
  int d = lane * 8;
  float wp[8];
#pragma unroll
  for (int j = 0; j < 8; ++j) wp[j] = ld_in(Wp, d + j, bf);
  // sdot0: 256 blocks x 4 waves x 16 positions
#pragma unroll 1
  for (int i = 0; i < 16; ++i) {
    int pos = (blockIdx.x * 4 + wv) * 16 + i;
    float sv[8];
#pragma unroll
    for (int j = 0; j < 8; ++j) sv[j] = ld_in(state, (long)pos * 512 + d + j, bf);
    float acc = sv[0] * wp[0];
#pragma unroll
    for (int j = 1; j < 8; ++j) acc = fmaf(sv[j], wp[j], acc);
#pragma unroll
    for (int off = 32; off > 0; off >>= 1) acc += __shfl_xor(acc, off, 64);
    if (lane == 0) pdot8[(long)pos * 8] = acc;
    if (lane >= 1 && lane < 8) pdot8[(long)pos * 8 + lane] = 0.f;
  }
  // edot[t] = dot(emb_t, Wp): blocks 0..10, wave 0
  if (blockIdx.x < 11 && wv == 0) {
    int t = blockIdx.x;
    float ev[8];
#pragma unroll
    for (int j = 0; j < 8; ++j) ev[j] = ld_in(emb, (long)t * 512 + d + j, bf);
    float acc = ev[0] * wp[0];
#pragma unroll
    for (int j = 1; j < 8; ++j) acc = fmaf(ev[j], wp[j], acc);
#pragma unroll
    for (int off = 32; off > 0; off >>= 1) acc += __shfl_xor(acc, off, 64);
    if (lane == 0) edot[t] = acc;
  }
}

// ---------- big conversions + weight transpose/split + zero init ----------
__global__ void k_init(const void* state, const void* W1, const void* W2,
                       const void* mask, float* stateF, unsigned short* w1t,
                       unsigned short* w2t, float* maskF, float* prevF,
                       float* hp, float* rem, float* nup, int* counts) {
  int bf = detect_bf(mask);
  long t = (long)blockIdx.x * blockDim.x + threadIdx.x;
  long st = (long)gridDim.x * blockDim.x;
  for (long i = t; i < 8388608L; i += st) {
    stateF[i] = ld_in(state, i, bf);
    prevF[i] = 0.f;
  }
  // W1 [512][2048] -> W1T planes [2048][512] bf16 x3 (plane stride 1048576)
  for (long i = t; i < 1048576L; i += st) {
    float v = ld_in(W1, i, bf);
    long n = i & 2047, k = i >> 11;
    unsigned short h, m, l;
    split3(v, h, m, l);
    long o = n * 512 + k;
    w1t[o] = h;
    w1t[1048576L + o] = m;
    w1t[2097152L + o] = l;
  }
  // W2 [2048][512] -> W2T planes [512][2048] bf16 x3
  for (long i = t; i < 1048576L; i += st) {
    float v = ld_in(W2, i, bf);
    long k = i >> 9, n = i & 511;
    unsigned short h, m, l;
    split3(v, h, m, l);
    long o = n * 2048 + k;
    w2t[o] = h;
    w2t[1048576L + o] = m;
    w2t[2097152L + o] = l;
  }
  for (long i = t; i < 16384L; i += st) {
    maskF[i] = ld_in(mask, i, bf);
    hp[i] = 0.f;
    rem[i] = 0.f;
    nup[i] = 0.f;
  }
  if (t < 11) counts[t] = 0;
}

// ---------- ponder-lite: 1 thread / position, no state read ---------------
__global__ __launch_bounds__(256) void k_plite(
    const float* __restrict__ pdot8, const float* __restrict__ edot,
    const float* __restrict__ bpF, float* hp, float* rem, float* nup,
    float* uw, int* __restrict__ count, int* __restrict__ ridx, int t) {
  int pos = blockIdx.x * 256 + threadIdx.x;
  float hpv = hp[pos];
  if (hpv >= 1.0f) return;  // halted forever
  const float* pd = pdot8 + (long)pos * 8;
  float s8 = pd[0];
#pragma unroll
  for (int k = 1; k < 8; ++k) s8 += pd[k];
  float p = 1.0f / (1.0f + expf(-(s8 + edot[t] + bpF[0])));
  float q = hpv + p;
  float nh = (q > THR) ? 1.0f : 0.0f;
  float st2 = (q <= THR) ? 1.0f : 0.0f;
  float hpn = hpv + p * st2;
  float remn = rem[pos] + nh * (1.0f - hpn);
  hpn = hpn + nh * remn;
  nup[pos] = nup[pos] + st2 + nh;
  uw[pos] = p * st2 + nh * remn;
  hp[pos] = hpn;
  rem[pos] = remn;
  int idx = atomicAdd(count, 1);
  ridx[idx] = pos;
}

// LDS (both GEMMs, dynamic 40960 B):
//   Au fp32 [4 q][2 h][128 rows][4] = 16384 B at 0
//   Bs bf16 [3 p][4 q][128 rows][8] = 24576 B at 16384
// Stage region = 1KB (64 lanes x 16B); R5 layouts, 0 bank conflicts verified.

// ---------- GEMM1: U = relu((state[ridx]+emb) * W1 + b1) -> U fp32 --------
// A: stateF gathered via ridx; emb added in-register from global (L1-res).
// B: W1T planes; K=512 (16 kt), N=2048; XCD-pinned swizzle (x = bid&7).
__global__ __launch_bounds__(256) void k_gemm1(
    const float* __restrict__ stateF, const float* __restrict__ embT,
    const unsigned short* __restrict__ w1t, const float* __restrict__ b1F,
    const int* __restrict__ count, const int* __restrict__ ridx,
    float* __restrict__ U, int c0, int mc) {
  int Ma = *count;
  int mEnd = c0 + mc;
  if (Ma < mEnd) mEnd = Ma;
  int f = blockIdx.x;
  int x = f & 7, s = f >> 3;
  int n0 = (x * 2 + (s & 1)) * 128;
  int m0 = c0 + (s >> 1) * 128;
  if (m0 >= mEnd) return;
  extern __shared__ __align__(16) char lds[];
  float* Au = (float*)lds;
  unsigned short* Bs = (unsigned short*)(lds + 16384);
  int tid = threadIdx.x;
  int lane = tid & 63, wv = tid >> 6;
  int quad = lane >> 4, ln15 = lane & 15;
  int wm = (wv >> 1) << 6, wn = (wv & 1) << 6;
  int rr0 = m0 + lane;
  if (rr0 >= mEnd) rr0 = mEnd - 1;
  int rr1 = m0 + 64 + lane;
  if (rr1 >= mEnd) rr1 = mEnd - 1;
  long pos0 = ridx[rr0], pos1 = ridx[rr1];
  f32x4 acc[4][4];
#pragma unroll
  for (int i = 0; i < 4; i++)
#pragma unroll
    for (int j = 0; j < 4; j++) acc[i][j] = (f32x4)0.f;
#pragma unroll 1
  for (int kt = 0; kt < 16; ++kt) {
    __syncthreads();
#pragma unroll
    for (int i = 0; i < 4; ++i) {  // A staging fp32 gather
      int g = wv + 4 * i;
      int q = g >> 2, h = (g >> 1) & 1, rh = g & 1;
      long po = rh ? pos1 : pos0;
      gld16(stateF + po * 512 + kt * 32 + q * 8 + h * 4,
            Au + ((q * 2 + h) * 128 + rh * 64) * 4);
    }
#pragma unroll
    for (int i = 0; i < 6; ++i) {  // B staging
      int g = wv + 4 * i;
      int p = g >> 3, q = (g >> 1) & 3, rh = g & 1;
      long n = n0 + rh * 64 + lane;
      gld16(w1t + (long)p * 1048576L + n * 512 + kt * 32 + q * 8,
            Bs + ((p * 4 + q) * 128 + rh * 64) * 8);
    }
    __syncthreads();
    float es[8];
    {
      f4 e0 = ld4(embT + kt * 32 + quad * 8);
      f4 e1 = ld4(embT + kt * 32 + quad * 8 + 4);
      es[0] = e0.x; es[1] = e0.y; es[2] = e0.z; es[3] = e0.w;
      es[4] = e1.x; es[5] = e1.y; es[6] = e1.z; es[7] = e1.w;
    }
    short8 af[3][4];
#pragma unroll
    for (int mt = 0; mt < 4; ++mt) {
      int row = wm + mt * 16 + ln15;
      f4 x0 = *(const f4*)(Au + ((quad * 2 + 0) * 128 + row) * 4);
      f4 x1 = *(const f4*)(Au + ((quad * 2 + 1) * 128 + row) * 4);
      float xs[8];
      xs[0] = x0.x + es[0]; xs[1] = x0.y + es[1];
      xs[2] = x0.z + es[2]; xs[3] = x0.w + es[3];
      xs[4] = x1.x + es[4]; xs[5] = x1.y + es[5];
      xs[6] = x1.z + es[6]; xs[7] = x1.w + es[7];
#pragma unroll
      for (int j = 0; j < 8; ++j) {
        unsigned short h_, m_, l_;
        split3(xs[j], h_, m_, l_);
        ((unsigned short*)&af[0][mt])[j] = h_;
        ((unsigned short*)&af[1][mt])[j] = m_;
        ((unsigned short*)&af[2][mt])[j] = l_;
      }
    }
    const unsigned short* bs = Bs + quad * 1024 + (wn + ln15) * 8;
#pragma unroll
    for (int pb = 0; pb < 3; ++pb) {
      short8 bfr[4];
#pragma unroll
      for (int nt = 0; nt < 4; ++nt)
        bfr[nt] = *(const short8*)(bs + pb * 4096 + nt * 128);
      int npa = (pb == 0) ? 3 : ((pb == 1) ? 2 : 1);
      for (int pa = 0; pa < npa; ++pa)
#pragma unroll
        for (int mt = 0; mt < 4; ++mt)
#pragma unroll
          for (int nt = 0; nt < 4; ++nt)
            acc[mt][nt] = MFMA16(af[pa][mt], bfr[nt], acc[mt][nt], 0, 0, 0);
    }
  }
#pragma unroll
  for (int mt = 0; mt < 4; ++mt)
#pragma unroll
    for (int reg = 0; reg < 4; ++reg) {
      int r = m0 + wm + mt * 16 + quad * 4 + reg;
      if (r < mEnd) {
        long lr = r - c0;
#pragma unroll
        for (int nt = 0; nt < 4; ++nt) {
          int n = n0 + wn + nt * 16 + ln15;
          U[lr * 2048 + n] = fmaxf(acc[mt][nt][reg] + b1F[n], 0.f);
        }
      }
    }
}

// ---------- GEMM2: h = U*W2 + b2; state=h*mask; prev += h*uw; pdot8 -------
// A: U fp32 local rows; B: W2T planes; K=2048 (64 kt), N=512.
// Epilogue also writes deterministic per-strip partials of dot(h, Wp):
// pdot8[pos*8 + (n0>>7)*2 + (wv&1)] (8 fixed slots per row, no atomics).
__global__ __launch_bounds__(256) void k_gemm2(
    const float* __restrict__ U, const unsigned short* __restrict__ w2t,
    const float* __restrict__ b2F, const int* __restrict__ count,
    const int* __restrict__ ridx, const float* __restrict__ maskF,
    const float* __restrict__ uwF, const float* __restrict__ WpF,
    float* __restrict__ stateF, float* __restrict__ prevF,
    float* __restrict__ pdot8, int c0, int mc) {
  int Ma = *count;
  int mEnd = c0 + mc;
  if (Ma < mEnd) mEnd = Ma;
  int f = blockIdx.x;
  int x = f & 7, s = f >> 3;
  int n0 = (x >> 1) * 128;
  int m0 = c0 + (s * 2 + (x & 1)) * 128;
  if (m0 >= mEnd) return;
  extern __shared__ __align__(16) char lds[];
  float* Au = (float*)lds;
  unsigned short* Bs = (unsigned short*)(lds + 16384);
  int tid = threadIdx.x;
  int lane = tid & 63, wv = tid >> 6;
  int quad = lane >> 4, ln15 = lane & 15;
  int wm = (wv >> 1) << 6, wn = (wv & 1) << 6;
  long lr0 = (long)(m0 - c0) + lane;
  long lr1 = lr0 + 64;
  f32x4 acc[4][4];
#pragma unroll
  for (int i = 0; i < 4; i++)
#pragma unroll
    for (int j = 0; j < 4; j++) acc[i][j] = (f32x4)0.f;
#pragma unroll 1
  for (int kt = 0; kt < 64; ++kt) {
    __syncthreads();
#pragma unroll
    for (int i = 0; i < 4; ++i) {  // A staging fp32
      int g = wv + 4 * i;
      int q = g >> 2, h = (g >> 1) & 1, rh = g & 1;
      long lr = rh ? lr1 : lr0;
      gld16(U + lr * 2048 + kt * 32 + q * 8 + h * 4,
            Au + ((q * 2 + h) * 128 + rh * 64) * 4);
    }
#pragma unroll
    for (int i = 0; i < 6; ++i) {  // B staging
      int g = wv + 4 * i;
      int p = g >> 3, q = (g >> 1) & 3, rh = g & 1;
      long n = n0 + rh * 64 + lane;
      gld16(w2t + (long)p * 1048576L + n * 2048 + kt * 32 + q * 8,
            Bs + ((p * 4 + q) * 128 + rh * 64) * 8);
    }
    __syncthreads();
    short8 af[3][4];
#pragma unroll
    for (int mt = 0; mt < 4; ++mt) {
      int row = wm + mt * 16 + ln15;
      f4 x0 = *(const f4*)(Au + ((quad * 2 + 0) * 128 + row) * 4);
      f4 x1 = *(const f4*)(Au + ((quad * 2 + 1) * 128 + row) * 4);
      float xs[8];
      xs[0] = x0.x; xs[1] = x0.y; xs[2] = x0.z; xs[3] = x0.w;
      xs[4] = x1.x; xs[5] = x1.y; xs[6] = x1.z; xs[7] = x1.w;
#pragma unroll
      for (int j = 0; j < 8; ++j) {
        unsigned short h_, m_, l_;
        split3(xs[j], h_, m_, l_);
        ((unsigned short*)&af[0][mt])[j] = h_;
        ((unsigned short*)&af[1][mt])[j] = m_;
        ((unsigned short*)&af[2][mt])[j] = l_;
      }
    }
    const unsigned short* bs = Bs + quad * 1024 + (wn + ln15) * 8;
#pragma unroll
    for (int pb = 0; pb < 3; ++pb) {
      short8 bfr[4];
#pragma unroll
      for (int nt = 0; nt < 4; ++nt)
        bfr[nt] = *(const short8*)(bs + pb * 4096 + nt * 128);
      int npa = (pb == 0) ? 3 : ((pb == 1) ? 2 : 1);
      for (int pa = 0; pa < npa; ++pa)
#pragma unroll
        for (int mt = 0; mt < 4; ++mt)
#pragma unroll
          for (int nt = 0; nt < 4; ++nt)
            acc[mt][nt] = MFMA16(af[pa][mt], bfr[nt], acc[mt][nt], 0, 0, 0);
    }
  }
#pragma unroll
  for (int mt = 0; mt < 4; ++mt)
#pragma unroll
    for (int reg = 0; reg < 4; ++reg) {
      int r = m0 + wm + mt * 16 + quad * 4 + reg;
      // r is uniform across the 16 ln15 lanes of each quad-group, so the
      // shfl_xor reduction below is exec-uniform within its group.
      if (r < mEnd) {
        long pos = (long)ridx[r];
        float mk = maskF[pos];
        float uv = uwF[pos];
        float pd = 0.f;
#pragma unroll
        for (int nt = 0; nt < 4; ++nt) {
          int n = n0 + wn + nt * 16 + ln15;
          float h = (acc[mt][nt][reg] + b2F[n]) * mk;
          long off = pos * 512 + n;
          stateF[off] = h;
          prevF[off] = fmaf(h, uv, prevF[off]);
          pd = fmaf(h, WpF[n], pd);
        }
        pd += __shfl_xor(pd, 1, 64);
        pd += __shfl_xor(pd, 2, 64);
        pd += __shfl_xor(pd, 4, 64);
        pd += __shfl_xor(pd, 8, 64);
        if (ln15 == 0)
          pdot8[pos * 8 + (long)((n0 >> 7) * 2 + (wv & 1))] = pd;
      }
    }
}

// ---------- final: concat outputs, cast per detected dtype ----------
__global__ void k_final(const float* prevF, const float* nupF,
                        const float* remF, void* out, const void* mask) {
  int bf = detect_bf(mask);
  long gt = (long)blockIdx.x * 256 + threadIdx.x;
  long gs = (long)gridDim.x * 256;
  for (long i = gt; i < 8421376L; i += gs) {
    float v;
    if (i < 8388608L) v = prevF[i];
    else if (i < 8404992L) v = nupF[i - 8388608L];
    else v = remF[i - 8404992L];
    if (bf) ((__hip_bfloat16*)out)[i] = __float2bfloat16(v);
    else ((float*)out)[i] = v;
  }
}

extern "C" void kernel_launch(void* const* d_in, const int* in_sizes, int n_in,
                              void* d_out, int out_size, void* d_ws,
                              size_t ws_size, hipStream_t stream) {
  const void* state = d_in[0];
  const void* mask = d_in[1];
  const void* emb = d_in[2];
  const void* Wp = d_in[3];
  const void* bp = d_in[4];
  const void* W1 = d_in[5];
  const void* b1 = d_in[6];
  const void* W2 = d_in[7];
  const void* b2 = d_in[8];
  char* w = (char*)d_ws;
  float* stateF = (float*)(w + 0L);
  float* prevF = (float*)(w + 33554432L);
  unsigned short* w1t = (unsigned short*)(w + 67108864L);  // 3 x 2 MB
  unsigned short* w2t = (unsigned short*)(w + 73400320L);  // 3 x 2 MB
  float* maskF = (float*)(w + 79691776L);
  float* hp = (float*)(w + 79757312L);
  float* rem = (float*)(w + 79822848L);
  float* nup = (float*)(w + 79888384L);
  float* uwf = (float*)(w + 79953920L);
  float* embF = (float*)(w + 80019456L);
  float* WpF = (float*)(w + 80052224L);
  float* b1F = (float*)(w + 80056320L);
  float* b2F = (float*)(w + 80064512L);
  float* bpF = (float*)(w + 80068608L);
  int* counts = (int*)(w + 80069120L);    // 11 ints
  float* edot = (float*)(w + 80069632L);  // 11 floats
  int* ridx = (int*)(w + 80070144L);      // 11 x 16384 x 4 B
  float* pdot8 = (float*)(w + 80791040L); // 16384 x 8 fp32 = 512 KB
  float* U = (float*)(w + 81315328L);     // fp32 [Mc][2048]
  long ub = (long)ws_size - 81315328L;
  long rows = ub / 8192L;
  long McL = rows & ~255L;  // multiple of 256 so T=mc/128 stays even
  if (McL > 16384L) McL = 16384L;
  if (McL < 256L) McL = 256L;
  int Mc = (int)McL;
  int nCh = (16384 + Mc - 1) / Mc;

  k_prep<<<256, 256, 0, stream>>>(mask, state, emb, Wp, bp, b1, b2, embF, WpF,
                                  bpF, b1F, b2F, pdot8, edot);
  k_init<<<2048, 256, 0, stream>>>(state, W1, W2, mask, stateF, w1t, w2t,
                                   maskF, prevF, hp, rem, nup, counts);
  for (int t = 0; t <= 10; t++) {
    k_plite<<<64, 256, 0, stream>>>(pdot8, edot, bpF, hp, rem, nup, uwf,
                                    counts + t, ridx + (long)t * 16384, t);
    for (int c = 0; c < nCh; c++) {
      int c0 = c * Mc;
      int mc = 16384 - c0;
      if (mc > Mc) mc = Mc;
      int T = mc / 128;  // even (Mc multiple of 256, 16384 multiple of 256)
      k_gemm1<<<T * 16, 256, 40960, stream>>>(stateF, embF + t * 512, w1t, b1F,
                                              counts + t,
                                              ridx + (long)t * 16384, U, c0,
                                              mc);
      k_gemm2<<<T * 4, 256, 40960, stream>>>(U, w2t, b2F, counts + t,
                                             ridx + (long)t * 16384, maskF,
                                             uwf, WpF, stateF, prevF, pdot8,
                                             c0, mc);
    }
  }
  k_final<<<2048, 256, 0, stream>>>(prevF, nup, rem, d_out, mask);
}

// Round 8
// 1575.569 us; speedup vs baseline: 1.8551x; 1.0671x over previous
//
#include <hip/hip_runtime.h>
#include <hip/hip_bf16.h>
#include <stdint.h>

// ACT (adaptive computation time) on MI355X.
// R13: repair R12's gemm1 regression. R12 post-mortem: total 1681us (ponder
// collapse + launch reduction validated) BUT k_gemm1 283us vs R5's proven
// 227us — the only diff was feeding emb via per-kt GLOBAL ld4 inside the
// K-loop (VGPR 84->120, MfmaUtil 40->31.5%: the loads share the vmcnt queue
// with global_load_lds staging and extend live ranges). R13 restores R5's
// embS: stage embT into 2KB LDS once before the loop, read es[] from LDS.
// Dynamic LDS 43008 (3 blocks/CU, R5's verified regime). Everything else
// identical to R12: k_prep/k_plite ponder elimination, pdot8 epilogue in
// gemm2, grid-strided k_final. Accumulation order kt->pb->pa->mt->nt
// bit-identical throughout.

#define THR 0.99f
typedef float4 f4;
typedef __attribute__((ext_vector_type(8))) short short8;
typedef __attribute__((ext_vector_type(4))) float f32x4;

__device__ __forceinline__ int detect_bf(const void* mask) {
  return (((const unsigned int*)mask)[0] == 0x3F803F80u) ? 1 : 0;
}

__device__ __forceinline__ float ld_in(const void* p, long i, int bf) {
  if (bf) {
    unsigned short u = ((const unsigned short*)p)[i];
    return __uint_as_float(((unsigned int)u) << 16);
  }
  return ((const float*)p)[i];
}
__device__ __forceinline__ f4 ld4(const float* p) { return *(const f4*)p; }

// truncation 3-way bf16 split: x ~= h + m + l, |err| <= 2^-24|x|
__device__ __forceinline__ void split3(float x, unsigned short& h,
                                       unsigned short& m, unsigned short& l) {
  unsigned u = __float_as_uint(x);
  h = (unsigned short)(u >> 16);
  float fh = __uint_as_float(u & 0xFFFF0000u);
  float r = x - fh;  // exact
  unsigned v = __float_as_uint(r);
  m = (unsigned short)(v >> 16);
  float fm = __uint_as_float(v & 0xFFFF0000u);
  l = (unsigned short)(__float_as_uint(r - fm) >> 16);
}

__device__ __forceinline__ void gld16(const void* g, void* l) {
  __builtin_amdgcn_global_load_lds(
      (const __attribute__((address_space(1))) void*)g,
      (__attribute__((address_space(3))) void*)l, 16, 0, 0);
}

#define MFMA16 __builtin_amdgcn_mfma_f32_16x16x32_bf16

// ---------- prep: small param conversion + sdot0 + edot -------------------
__global__ __launch_bounds__(256) void k_prep(
    const void* mask, const void* state, const void* emb, const void* Wp,
    const void* bp, const void* b1, const void* b2, float* embF, float* WpF,
    float* bpF, float* b1F, float* b2F, float* pdot8, float* edot) {
  int bf = detect_bf(mask);
  int tid = threadIdx.x;
  long gt = (long)blockIdx.x * 256 + tid;
  long gs = (long)gridDim.x * 256;
  for (long i = gt; i < 5632; i += gs) embF[i] = ld_in(emb, i, bf);
  for (long i = gt; i < 512; i += gs) {
    WpF[i] = ld_in(Wp, i, bf);
    b2F[i] = ld_in(b2, i, bf);
  }
  for (long i = gt; i < 2048; i += gs) b1F[i] = ld_in(b1, i, bf);
  if (gt == 0) bpF[0] = ld_in(bp, 0, bf);
  int lane = tid & 63, wv = tid >> 6;
  int d = lane * 8;
  float wp[8];
#pragma unroll
  for (int j = 0; j < 8; ++j) wp[j] = ld_in(Wp, d + j, bf);
  // sdot0: 256 blocks x 4 waves x 16 positions
#pragma unroll 1
  for (int i = 0; i < 16; ++i) {
    int pos = (blockIdx.x * 4 + wv) * 16 + i;
    float sv[8];
#pragma unroll
    for (int j = 0; j < 8; ++j) sv[j] = ld_in(state, (long)pos * 512 + d + j, bf);
    float acc = sv[0] * wp[0];
#pragma unroll
    for (int j = 1; j < 8; ++j) acc = fmaf(sv[j], wp[j], acc);
#pragma unroll
    for (int off = 32; off > 0; off >>= 1) acc += __shfl_xor(acc, off, 64);
    if (lane == 0) pdot8[(long)pos * 8] = acc;
    if (lane >= 1 && lane < 8) pdot8[(long)pos * 8 + lane] = 0.f;
  }
  // edot[t] = dot(emb_t, Wp): blocks 0..10, wave 0
  if (blockIdx.x < 11 && wv == 0) {
    int t = blockIdx.x;
    float ev[8];
#pragma unroll
    for (int j = 0; j < 8; ++j) ev[j] = ld_in(emb, (long)t * 512 + d + j, bf);
    float acc = ev[0] * wp[0];
#pragma unroll
    for (int j = 1; j < 8; ++j) acc = fmaf(ev[j], wp[j], acc);
#pragma unroll
    for (int off = 32; off > 0; off >>= 1) acc += __shfl_xor(acc, off, 64);
    if (lane == 0) edot[t] = acc;
  }
}

// ---------- big conversions + weight transpose/split + zero init ----------
__global__ void k_init(const void* state, const void* W1, const void* W2,
                       const void* mask, float* stateF, unsigned short* w1t,
                       unsigned short* w2t, float* maskF, float* prevF,
                       float* hp, float* rem, float* nup, int* counts) {
  int bf = detect_bf(mask);
  long t = (long)blockIdx.x * blockDim.x + threadIdx.x;
  long st = (long)gridDim.x * blockDim.x;
  for (long i = t; i < 8388608L; i += st) {
    stateF[i] = ld_in(state, i, bf);
    prevF[i] = 0.f;
  }
  // W1 [512][2048] -> W1T planes [2048][512] bf16 x3 (plane stride 1048576)
  for (long i = t; i < 1048576L; i += st) {
    float v = ld_in(W1, i, bf);
    long n = i & 2047, k = i >> 11;
    unsigned short h, m, l;
    split3(v, h, m, l);
    long o = n * 512 + k;
    w1t[o] = h;
    w1t[1048576L + o] = m;
    w1t[2097152L + o] = l;
  }
  // W2 [2048][512] -> W2T planes [512][2048] bf16 x3
  for (long i = t; i < 1048576L; i += st) {
    float v = ld_in(W2, i, bf);
    long k = i >> 9, n = i & 511;
    unsigned short h, m, l;
    split3(v, h, m, l);
    long o = n * 2048 + k;
    w2t[o] = h;
    w2t[1048576L + o] = m;
    w2t[2097152L + o] = l;
  }
  for (long i = t; i < 16384L; i += st) {
    maskF[i] = ld_in(mask, i, bf);
    hp[i] = 0.f;
    rem[i] = 0.f;
    nup[i] = 0.f;
  }
  if (t < 11) counts[t] = 0;
}

// ---------- ponder-lite: 1 thread / position, no state read ---------------
__global__ __launch_bounds__(256) void k_plite(
    const float* __restrict__ pdot8, const float* __restrict__ edot,
    const float* __restrict__ bpF, float* hp, float* rem, float* nup,
    float* uw, int* __restrict__ count, int* __restrict__ ridx, int t) {
  int pos = blockIdx.x * 256 + threadIdx.x;
  float hpv = hp[pos];
  if (hpv >= 1.0f) return;  // halted forever
  const float* pd = pdot8 + (long)pos * 8;
  float s8 = pd[0];
#pragma unroll
  for (int k = 1; k < 8; ++k) s8 += pd[k];
  float p = 1.0f / (1.0f + expf(-(s8 + edot[t] + bpF[0])));
  float q = hpv + p;
  float nh = (q > THR) ? 1.0f : 0.0f;
  float st2 = (q <= THR) ? 1.0f : 0.0f;
  float hpn = hpv + p * st2;
  float remn = rem[pos] + nh * (1.0f - hpn);
  hpn = hpn + nh * remn;
  nup[pos] = nup[pos] + st2 + nh;
  uw[pos] = p * st2 + nh * remn;
  hp[pos] = hpn;
  rem[pos] = remn;
  int idx = atomicAdd(count, 1);
  ridx[idx] = pos;
}

// LDS:
//   gemm1 (43008 B): Au fp32 16384 at 0; Bs bf16 24576 at 16384;
//                    embS fp32 2048 at 40960 (staged once).
//   gemm2 (40960 B): Au at 0; Bs at 16384.
// Stage region = 1KB (64 lanes x 16B); R5 layouts, 0 bank conflicts verified.

// ---------- GEMM1: U = relu((state[ridx]+emb) * W1 + b1) -> U fp32 --------
// A: stateF gathered via ridx; emb from embS LDS (staged once, R5 pattern).
// B: W1T planes; K=512 (16 kt), N=2048; XCD-pinned swizzle (x = bid&7).
__global__ __launch_bounds__(256) void k_gemm1(
    const float* __restrict__ stateF, const float* __restrict__ embT,
    const unsigned short* __restrict__ w1t, const float* __restrict__ b1F,
    const int* __restrict__ count, const int* __restrict__ ridx,
    float* __restrict__ U, int c0, int mc) {
  int Ma = *count;
  int mEnd = c0 + mc;
  if (Ma < mEnd) mEnd = Ma;
  int f = blockIdx.x;
  int x = f & 7, s = f >> 3;
  int n0 = (x * 2 + (s & 1)) * 128;
  int m0 = c0 + (s >> 1) * 128;
  if (m0 >= mEnd) return;
  extern __shared__ __align__(16) char lds[];
  float* Au = (float*)lds;
  unsigned short* Bs = (unsigned short*)(lds + 16384);
  float* embS = (float*)(lds + 40960);
  int tid = threadIdx.x;
  int lane = tid & 63, wv = tid >> 6;
  int quad = lane >> 4, ln15 = lane & 15;
  int wm = (wv >> 1) << 6, wn = (wv & 1) << 6;
  if (tid < 128) *(f4*)&embS[tid * 4] = ld4(embT + tid * 4);
  int rr0 = m0 + lane;
  if (rr0 >= mEnd) rr0 = mEnd - 1;
  int rr1 = m0 + 64 + lane;
  if (rr1 >= mEnd) rr1 = mEnd - 1;
  long pos0 = ridx[rr0], pos1 = ridx[rr1];
  f32x4 acc[4][4];
#pragma unroll
  for (int i = 0; i < 4; i++)
#pragma unroll
    for (int j = 0; j < 4; j++) acc[i][j] = (f32x4)0.f;
#pragma unroll 1
  for (int kt = 0; kt < 16; ++kt) {
    __syncthreads();
#pragma unroll
    for (int i = 0; i < 4; ++i) {  // A staging fp32 gather
      int g = wv + 4 * i;
      int q = g >> 2, h = (g >> 1) & 1, rh = g & 1;
      long po = rh ? pos1 : pos0;
      gld16(stateF + po * 512 + kt * 32 + q * 8 + h * 4,
            Au + ((q * 2 + h) * 128 + rh * 64) * 4);
    }
#pragma unroll
    for (int i = 0; i < 6; ++i) {  // B staging
      int g = wv + 4 * i;
      int p = g >> 3, q = (g >> 1) & 3, rh = g & 1;
      long n = n0 + rh * 64 + lane;
      gld16(w1t + (long)p * 1048576L + n * 512 + kt * 32 + q * 8,
            Bs + ((p * 4 + q) * 128 + rh * 64) * 8);
    }
    __syncthreads();
    float es[8];
    {
      f4 e0 = *(const f4*)&embS[kt * 32 + quad * 8];
      f4 e1 = *(const f4*)&embS[kt * 32 + quad * 8 + 4];
      es[0] = e0.x; es[1] = e0.y; es[2] = e0.z; es[3] = e0.w;
      es[4] = e1.x; es[5] = e1.y; es[6] = e1.z; es[7] = e1.w;
    }
    short8 af[3][4];
#pragma unroll
    for (int mt = 0; mt < 4; ++mt) {
      int row = wm + mt * 16 + ln15;
      f4 x0 = *(const f4*)(Au + ((quad * 2 + 0) * 128 + row) * 4);
      f4 x1 = *(const f4*)(Au + ((quad * 2 + 1) * 128 + row) * 4);
      float xs[8];
      xs[0] = x0.x + es[0]; xs[1] = x0.y + es[1];
      xs[2] = x0.z + es[2]; xs[3] = x0.w + es[3];
      xs[4] = x1.x + es[4]; xs[5] = x1.y + es[5];
      xs[6] = x1.z + es[6]; xs[7] = x1.w + es[7];
#pragma unroll
      for (int j = 0; j < 8; ++j) {
        unsigned short h_, m_, l_;
        split3(xs[j], h_, m_, l_);
        ((unsigned short*)&af[0][mt])[j] = h_;
        ((unsigned short*)&af[1][mt])[j] = m_;
        ((unsigned short*)&af[2][mt])[j] = l_;
      }
    }
    const unsigned short* bs = Bs + quad * 1024 + (wn + ln15) * 8;
#pragma unroll
    for (int pb = 0; pb < 3; ++pb) {
      short8 bfr[4];
#pragma unroll
      for (int nt = 0; nt < 4; ++nt)
        bfr[nt] = *(const short8*)(bs + pb * 4096 + nt * 128);
      int npa = (pb == 0) ? 3 : ((pb == 1) ? 2 : 1);
      for (int pa = 0; pa < npa; ++pa)
#pragma unroll
        for (int mt = 0; mt < 4; ++mt)
#pragma unroll
          for (int nt = 0; nt < 4; ++nt)
            acc[mt][nt] = MFMA16(af[pa][mt], bfr[nt], acc[mt][nt], 0, 0, 0);
    }
  }
#pragma unroll
  for (int mt = 0; mt < 4; ++mt)
#pragma unroll
    for (int reg = 0; reg < 4; ++reg) {
      int r = m0 + wm + mt * 16 + quad * 4 + reg;
      if (r < mEnd) {
        long lr = r - c0;
#pragma unroll
        for (int nt = 0; nt < 4; ++nt) {
          int n = n0 + wn + nt * 16 + ln15;
          U[lr * 2048 + n] = fmaxf(acc[mt][nt][reg] + b1F[n], 0.f);
        }
      }
    }
}

// ---------- GEMM2: h = U*W2 + b2; state=h*mask; prev += h*uw; pdot8 -------
// A: U fp32 local rows; B: W2T planes; K=2048 (64 kt), N=512.
// Epilogue also writes deterministic per-strip partials of dot(h, Wp):
// pdot8[pos*8 + (n0>>7)*2 + (wv&1)] (8 fixed slots per row, no atomics).
__global__ __launch_bounds__(256) void k_gemm2(
    const float* __restrict__ U, const unsigned short* __restrict__ w2t,
    const float* __restrict__ b2F, const int* __restrict__ count,
    const int* __restrict__ ridx, const float* __restrict__ maskF,
    const float* __restrict__ uwF, const float* __restrict__ WpF,
    float* __restrict__ stateF, float* __restrict__ prevF,
    float* __restrict__ pdot8, int c0, int mc) {
  int Ma = *count;
  int mEnd = c0 + mc;
  if (Ma < mEnd) mEnd = Ma;
  int f = blockIdx.x;
  int x = f & 7, s = f >> 3;
  int n0 = (x >> 1) * 128;
  int m0 = c0 + (s * 2 + (x & 1)) * 128;
  if (m0 >= mEnd) return;
  extern __shared__ __align__(16) char lds[];
  float* Au = (float*)lds;
  unsigned short* Bs = (unsigned short*)(lds + 16384);
  int tid = threadIdx.x;
  int lane = tid & 63, wv = tid >> 6;
  int quad = lane >> 4, ln15 = lane & 15;
  int wm = (wv >> 1) << 6, wn = (wv & 1) << 6;
  long lr0 = (long)(m0 - c0) + lane;
  long lr1 = lr0 + 64;
  f32x4 acc[4][4];
#pragma unroll
  for (int i = 0; i < 4; i++)
#pragma unroll
    for (int j = 0; j < 4; j++) acc[i][j] = (f32x4)0.f;
#pragma unroll 1
  for (int kt = 0; kt < 64; ++kt) {
    __syncthreads();
#pragma unroll
    for (int i = 0; i < 4; ++i) {  // A staging fp32
      int g = wv + 4 * i;
      int q = g >> 2, h = (g >> 1) & 1, rh = g & 1;
      long lr = rh ? lr1 : lr0;
      gld16(U + lr * 2048 + kt * 32 + q * 8 + h * 4,
            Au + ((q * 2 + h) * 128 + rh * 64) * 4);
    }
#pragma unroll
    for (int i = 0; i < 6; ++i) {  // B staging
      int g = wv + 4 * i;
      int p = g >> 3, q = (g >> 1) & 3, rh = g & 1;
      long n = n0 + rh * 64 + lane;
      gld16(w2t + (long)p * 1048576L + n * 2048 + kt * 32 + q * 8,
            Bs + ((p * 4 + q) * 128 + rh * 64) * 8);
    }
    __syncthreads();
    short8 af[3][4];
#pragma unroll
    for (int mt = 0; mt < 4; ++mt) {
      int row = wm + mt * 16 + ln15;
      f4 x0 = *(const f4*)(Au + ((quad * 2 + 0) * 128 + row) * 4);
      f4 x1 = *(const f4*)(Au + ((quad * 2 + 1) * 128 + row) * 4);
      float xs[8];
      xs[0] = x0.x; xs[1] = x0.y; xs[2] = x0.z; xs[3] = x0.w;
      xs[4] = x1.x; xs[5] = x1.y; xs[6] = x1.z; xs[7] = x1.w;
#pragma unroll
      for (int j = 0; j < 8; ++j) {
        unsigned short h_, m_, l_;
        split3(xs[j], h_, m_, l_);
        ((unsigned short*)&af[0][mt])[j] = h_;
        ((unsigned short*)&af[1][mt])[j] = m_;
        ((unsigned short*)&af[2][mt])[j] = l_;
      }
    }
    const unsigned short* bs = Bs + quad * 1024 + (wn + ln15) * 8;
#pragma unroll
    for (int pb = 0; pb < 3; ++pb) {
      short8 bfr[4];
#pragma unroll
      for (int nt = 0; nt < 4; ++nt)
        bfr[nt] = *(const short8*)(bs + pb * 4096 + nt * 128);
      int npa = (pb == 0) ? 3 : ((pb == 1) ? 2 : 1);
      for (int pa = 0; pa < npa; ++pa)
#pragma unroll
        for (int mt = 0; mt < 4; ++mt)
#pragma unroll
          for (int nt = 0; nt < 4; ++nt)
            acc[mt][nt] = MFMA16(af[pa][mt], bfr[nt], acc[mt][nt], 0, 0, 0);
    }
  }
#pragma unroll
  for (int mt = 0; mt < 4; ++mt)
#pragma unroll
    for (int reg = 0; reg < 4; ++reg) {
      int r = m0 + wm + mt * 16 + quad * 4 + reg;
      // r is uniform across the 16 ln15 lanes of each quad-group, so the
      // shfl_xor reduction below is exec-uniform within its group.
      if (r < mEnd) {
        long pos = (long)ridx[r];
        float mk = maskF[pos];
        float uv = uwF[pos];
        float pd = 0.f;
#pragma unroll
        for (int nt = 0; nt < 4; ++nt) {
          int n = n0 + wn + nt * 16 + ln15;
          float h = (acc[mt][nt][reg] + b2F[n]) * mk;
          long off = pos * 512 + n;
          stateF[off] = h;
          prevF[off] = fmaf(h, uv, prevF[off]);
          pd = fmaf(h, WpF[n], pd);
        }
        pd += __shfl_xor(pd, 1, 64);
        pd += __shfl_xor(pd, 2, 64);
        pd += __shfl_xor(pd, 4, 64);
        pd += __shfl_xor(pd, 8, 64);
        if (ln15 == 0)
          pdot8[pos * 8 + (long)((n0 >> 7) * 2 + (wv & 1))] = pd;
      }
    }
}

// ---------- final: concat outputs, cast per detected dtype ----------
__global__ void k_final(const float* prevF, const float* nupF,
                        const float* remF, void* out, const void* mask) {
  int bf = detect_bf(mask);
  long gt = (long)blockIdx.x * 256 + threadIdx.x;
  long gs = (long)gridDim.x * 256;
  for (long i = gt; i < 8421376L; i += gs) {
    float v;
    if (i < 8388608L) v = prevF[i];
    else if (i < 8404992L) v = nupF[i - 8388608L];
    else v = remF[i - 8404992L];
    if (bf) ((__hip_bfloat16*)out)[i] = __float2bfloat16(v);
    else ((float*)out)[i] = v;
  }
}

extern "C" void kernel_launch(void* const* d_in, const int* in_sizes, int n_in,
                              void* d_out, int out_size, void* d_ws,
                              size_t ws_size, hipStream_t stream) {
  const void* state = d_in[0];
  const void* mask = d_in[1];
  const void* emb = d_in[2];
  const void* Wp = d_in[3];
  const void* bp = d_in[4];
  const void* W1 = d_in[5];
  const void* b1 = d_in[6];
  const void* W2 = d_in[7];
  const void* b2 = d_in[8];
  char* w = (char*)d_ws;
  float* stateF = (float*)(w + 0L);
  float* prevF = (float*)(w + 33554432L);
  unsigned short* w1t = (unsigned short*)(w + 67108864L);  // 3 x 2 MB
  unsigned short* w2t = (unsigned short*)(w + 73400320L);  // 3 x 2 MB
  float* maskF = (float*)(w + 79691776L);
  float* hp = (float*)(w + 79757312L);
  float* rem = (float*)(w + 79822848L);
  float* nup = (float*)(w + 79888384L);
  float* uwf = (float*)(w + 79953920L);
  float* embF = (float*)(w + 80019456L);
  float* WpF = (float*)(w + 80052224L);
  float* b1F = (float*)(w + 80056320L);
  float* b2F = (float*)(w + 80064512L);
  float* bpF = (float*)(w + 80068608L);
  int* counts = (int*)(w + 80069120L);    // 11 ints
  float* edot = (float*)(w + 80069632L);  // 11 floats
  int* ridx = (int*)(w + 80070144L);      // 11 x 16384 x 4 B
  float* pdot8 = (float*)(w + 80791040L); // 16384 x 8 fp32 = 512 KB
  float* U = (float*)(w + 81315328L);     // fp32 [Mc][2048]
  long ub = (long)ws_size - 81315328L;
  long rows = ub / 8192L;
  long McL = rows & ~255L;  // multiple of 256 so T=mc/128 stays even
  if (McL > 16384L) McL = 16384L;
  if (McL < 256L) McL = 256L;
  int Mc = (int)McL;
  int nCh = (16384 + Mc - 1) / Mc;

  k_prep<<<256, 256, 0, stream>>>(mask, state, emb, Wp, bp, b1, b2, embF, WpF,
                                  bpF, b1F, b2F, pdot8, edot);
  k_init<<<2048, 256, 0, stream>>>(state, W1, W2, mask, stateF, w1t, w2t,
                                   maskF, prevF, hp, rem, nup, counts);
  for (int t = 0; t <= 10; t++) {
    k_plite<<<64, 256, 0, stream>>>(pdot8, edot, bpF, hp, rem, nup, uwf,
                                    counts + t, ridx + (long)t * 16384, t);
    for (int c = 0; c < nCh; c++) {
      int c0 = c * Mc;
      int mc = 16384 - c0;
      if (mc > Mc) mc = Mc;
      int T = mc / 128;  // even (Mc multiple of 256, 16384 multiple of 256)
      k_gemm1<<<T * 16, 256, 43008, stream>>>(stateF, embF + t * 512, w1t, b1F,
                                              counts + t,
                                              ridx + (long)t * 16384, U, c0,
                                              mc);
      k_gemm2<<<T * 4, 256, 40960, stream>>>(U, w2t, b2F, counts + t,
                                             ridx + (long)t * 16384, maskF,
                                             uwf, WpF, stateF, prevF, pdot8,
                                             c0, mc);
    }
  }
  k_final<<<2048, 256, 0, stream>>>(prevF, nup, rem, d_out, mask);
}

// Round 9
// 1560.640 us; speedup vs baseline: 1.8728x; 1.0096x over previous
//
#include <hip/hip_runtime.h>
#include <hip/hip_bf16.h>
#include <stdint.h>

// ACT (adaptive computation time) on MI355X.
// R14: static-LDS restoration. R13 post-mortem: gemm1 247us/VGPR116/SGPR32
// vs R5's 227us/VGPR84/SGPR112 — the only diff was dynamic extern __shared__
// (base pointer in VGPRs, offsets computed per access) vs R5's static
// __shared__ arrays (offsets folded into ds-instruction immediates, uniform
// bases in SGPRs). R14 restores the exact R5 static declarations in both
// GEMMs. Also fuses sdot0 into k_init (row-based: state copy + prevF zero +
// dot(row,Wp) in one pass) removing k_prep's duplicate 32MB state read.
// Everything else = R13: k_plite ponder (validated), pdot8 epilogue in
// gemm2, grid-strided k_final. Accumulation order kt->pb->pa->mt->nt
// bit-identical throughout; absmax has stayed 0.0078125 (pure bf16 output
// rounding) across all rounds.

#define THR 0.99f
typedef float4 f4;
typedef __attribute__((ext_vector_type(8))) short short8;
typedef __attribute__((ext_vector_type(4))) float f32x4;

__device__ __forceinline__ int detect_bf(const void* mask) {
  return (((const unsigned int*)mask)[0] == 0x3F803F80u) ? 1 : 0;
}

__device__ __forceinline__ float ld_in(const void* p, long i, int bf) {
  if (bf) {
    unsigned short u = ((const unsigned short*)p)[i];
    return __uint_as_float(((unsigned int)u) << 16);
  }
  return ((const float*)p)[i];
}
__device__ __forceinline__ f4 ld4(const float* p) { return *(const f4*)p; }

// truncation 3-way bf16 split: x ~= h + m + l, |err| <= 2^-24|x|
__device__ __forceinline__ void split3(float x, unsigned short& h,
                                       unsigned short& m, unsigned short& l) {
  unsigned u = __float_as_uint(x);
  h = (unsigned short)(u >> 16);
  float fh = __uint_as_float(u & 0xFFFF0000u);
  float r = x - fh;  // exact
  unsigned v = __float_as_uint(r);
  m = (unsigned short)(v >> 16);
  float fm = __uint_as_float(v & 0xFFFF0000u);
  l = (unsigned short)(__float_as_uint(r - fm) >> 16);
}

__device__ __forceinline__ void gld16(const void* g, void* l) {
  __builtin_amdgcn_global_load_lds(
      (const __attribute__((address_space(1))) void*)g,
      (__attribute__((address_space(3))) void*)l, 16, 0, 0);
}

#define MFMA16 __builtin_amdgcn_mfma_f32_16x16x32_bf16

// ---------- prep: small param conversion + edot ---------------------------
__global__ __launch_bounds__(256) void k_prep(
    const void* mask, const void* emb, const void* Wp, const void* bp,
    const void* b1, const void* b2, float* embF, float* WpF, float* bpF,
    float* b1F, float* b2F, float* edot) {
  int bf = detect_bf(mask);
  int tid = threadIdx.x;
  long gt = (long)blockIdx.x * 256 + tid;
  long gs = (long)gridDim.x * 256;
  for (long i = gt; i < 5632; i += gs) embF[i] = ld_in(emb, i, bf);
  for (long i = gt; i < 512; i += gs) {
    WpF[i] = ld_in(Wp, i, bf);
    b2F[i] = ld_in(b2, i, bf);
  }
  for (long i = gt; i < 2048; i += gs) b1F[i] = ld_in(b1, i, bf);
  if (gt == 0) bpF[0] = ld_in(bp, 0, bf);
  // edot[t] = dot(emb_t, Wp): blocks 0..10, wave 0
  int lane = tid & 63, wv = tid >> 6;
  if (blockIdx.x < 11 && wv == 0) {
    int t = blockIdx.x;
    int d = lane * 8;
    float acc = 0.f;
#pragma unroll
    for (int j = 0; j < 8; ++j) {
      float wpv = ld_in(Wp, d + j, bf);
      float ev = ld_in(emb, (long)t * 512 + d + j, bf);
      acc = (j == 0) ? ev * wpv : fmaf(ev, wpv, acc);
    }
#pragma unroll
    for (int off = 32; off > 0; off >>= 1) acc += __shfl_xor(acc, off, 64);
    if (lane == 0) edot[t] = acc;
  }
}

// ---------- big conversions + weight transpose/split + sdot0 --------------
// Row-based state pass: 2048 blocks x 4 waves x 2 rows = 16384 rows.
// Each wave copies its rows to stateF, zeroes prevF, and reduces
// dot(row, Wp) -> pdot8[row*8] (slots 1..7 zeroed) in the same pass.
__global__ __launch_bounds__(256) void k_init(
    const void* state, const void* W1, const void* W2, const void* mask,
    const void* Wp, float* stateF, unsigned short* w1t, unsigned short* w2t,
    float* maskF, float* prevF, float* hp, float* rem, float* nup,
    float* pdot8, int* counts) {
  int bf = detect_bf(mask);
  int tid = threadIdx.x;
  int lane = tid & 63, wv = tid >> 6;
  int d = lane * 8;
  float wp[8];
#pragma unroll
  for (int j = 0; j < 8; ++j) wp[j] = ld_in(Wp, d + j, bf);
#pragma unroll 1
  for (int r = 0; r < 2; ++r) {
    long row = ((long)blockIdx.x * 4 + wv) * 2 + r;
    long base = row * 512 + d;
    float sv[8];
#pragma unroll
    for (int j = 0; j < 8; ++j) sv[j] = ld_in(state, base + j, bf);
    f4 y0, y1;
    y0.x = sv[0]; y0.y = sv[1]; y0.z = sv[2]; y0.w = sv[3];
    y1.x = sv[4]; y1.y = sv[5]; y1.z = sv[6]; y1.w = sv[7];
    *(f4*)&stateF[base] = y0;
    *(f4*)&stateF[base + 4] = y1;
    *(f4*)&prevF[base] = (f4){0.f, 0.f, 0.f, 0.f};
    *(f4*)&prevF[base + 4] = (f4){0.f, 0.f, 0.f, 0.f};
    float acc = sv[0] * wp[0];
#pragma unroll
    for (int j = 1; j < 8; ++j) acc = fmaf(sv[j], wp[j], acc);
#pragma unroll
    for (int off = 32; off > 0; off >>= 1) acc += __shfl_xor(acc, off, 64);
    if (lane == 0) pdot8[row * 8] = acc;
    if (lane >= 1 && lane < 8) pdot8[row * 8 + lane] = 0.f;
  }
  long t = (long)blockIdx.x * blockDim.x + tid;
  long st = (long)gridDim.x * blockDim.x;
  // W1 [512][2048] -> W1T planes [2048][512] bf16 x3 (plane stride 1048576)
  for (long i = t; i < 1048576L; i += st) {
    float v = ld_in(W1, i, bf);
    long n = i & 2047, k = i >> 11;
    unsigned short h, m, l;
    split3(v, h, m, l);
    long o = n * 512 + k;
    w1t[o] = h;
    w1t[1048576L + o] = m;
    w1t[2097152L + o] = l;
  }
  // W2 [2048][512] -> W2T planes [512][2048] bf16 x3
  for (long i = t; i < 1048576L; i += st) {
    float v = ld_in(W2, i, bf);
    long k = i >> 9, n = i & 511;
    unsigned short h, m, l;
    split3(v, h, m, l);
    long o = n * 2048 + k;
    w2t[o] = h;
    w2t[1048576L + o] = m;
    w2t[2097152L + o] = l;
  }
  for (long i = t; i < 16384L; i += st) {
    maskF[i] = ld_in(mask, i, bf);
    hp[i] = 0.f;
    rem[i] = 0.f;
    nup[i] = 0.f;
  }
  if (t < 11) counts[t] = 0;
}

// ---------- ponder-lite: 1 thread / position, no state read ---------------
__global__ __launch_bounds__(256) void k_plite(
    const float* __restrict__ pdot8, const float* __restrict__ edot,
    const float* __restrict__ bpF, float* hp, float* rem, float* nup,
    float* uw, int* __restrict__ count, int* __restrict__ ridx, int t) {
  int pos = blockIdx.x * 256 + threadIdx.x;
  float hpv = hp[pos];
  if (hpv >= 1.0f) return;  // halted forever
  const float* pd = pdot8 + (long)pos * 8;
  float s8 = pd[0];
#pragma unroll
  for (int k = 1; k < 8; ++k) s8 += pd[k];
  float p = 1.0f / (1.0f + expf(-(s8 + edot[t] + bpF[0])));
  float q = hpv + p;
  float nh = (q > THR) ? 1.0f : 0.0f;
  float st2 = (q <= THR) ? 1.0f : 0.0f;
  float hpn = hpv + p * st2;
  float remn = rem[pos] + nh * (1.0f - hpn);
  hpn = hpn + nh * remn;
  nup[pos] = nup[pos] + st2 + nh;
  uw[pos] = p * st2 + nh * remn;
  hp[pos] = hpn;
  rem[pos] = remn;
  int idx = atomicAdd(count, 1);
  ridx[idx] = pos;
}

// LDS (static, both GEMMs): Au fp32 [4 q][2 h][128 rows][4] = 16 KB;
// Bs bf16 [3 p][4 q][128 rows][8] = 24 KB; gemm1 adds embS[512] = 2 KB.
// Static __shared__ so ds offsets fold into instruction immediates and
// uniform bases live in SGPRs (R5's 84-VGPR/112-SGPR regime).
// Stage region = 1KB (64 lanes x 16B); R5 layouts, 0 bank conflicts verified.

// ---------- GEMM1: U = relu((state[ridx]+emb) * W1 + b1) -> U fp32 --------
// A: stateF gathered via ridx; emb from embS LDS (staged once).
// B: W1T planes; K=512 (16 kt), N=2048; XCD-pinned swizzle (x = bid&7).
__global__ __launch_bounds__(256) void k_gemm1(
    const float* __restrict__ stateF, const float* __restrict__ embT,
    const unsigned short* __restrict__ w1t, const float* __restrict__ b1F,
    const int* __restrict__ count, const int* __restrict__ ridx,
    float* __restrict__ U, int c0, int mc) {
  int Ma = *count;
  int mEnd = c0 + mc;
  if (Ma < mEnd) mEnd = Ma;
  int f = blockIdx.x;
  int x = f & 7, s = f >> 3;
  int n0 = (x * 2 + (s & 1)) * 128;
  int m0 = c0 + (s >> 3 ? 0 : (s >> 1)) * 128;  // placeholder removed below
  m0 = c0 + (s >> 1) * 128;
  if (m0 >= mEnd) return;
  __shared__ __align__(16) float Au[4][2][128][4];          // 16 KB fp32 A
  __shared__ __align__(16) unsigned short Bs[3][4][128][8]; // 24 KB B planes
  __shared__ __align__(16) float embS[512];
  int tid = threadIdx.x;
  int lane = tid & 63, wv = tid >> 6;
  int quad = lane >> 4, ln15 = lane & 15;
  int wm = (wv >> 1) << 6, wn = (wv & 1) << 6;
  if (tid < 128) *(f4*)&embS[tid * 4] = ld4(embT + tid * 4);
  int rr0 = m0 + lane;
  if (rr0 >= mEnd) rr0 = mEnd - 1;
  int rr1 = m0 + 64 + lane;
  if (rr1 >= mEnd) rr1 = mEnd - 1;
  long pos0 = ridx[rr0], pos1 = ridx[rr1];
  f32x4 acc[4][4];
#pragma unroll
  for (int i = 0; i < 4; i++)
#pragma unroll
    for (int j = 0; j < 4; j++) acc[i][j] = (f32x4)0.f;
#pragma unroll 1
  for (int kt = 0; kt < 16; ++kt) {
    __syncthreads();
#pragma unroll
    for (int i = 0; i < 4; ++i) {  // A staging fp32 gather
      int g = wv + 4 * i;
      int q = g >> 2, h = (g >> 1) & 1, rh = g & 1;
      long po = rh ? pos1 : pos0;
      gld16(stateF + po * 512 + kt * 32 + q * 8 + h * 4,
            &Au[q][h][rh * 64][0]);
    }
#pragma unroll
    for (int i = 0; i < 6; ++i) {  // B staging
      int g = wv + 4 * i;
      int p = g >> 3, q = (g >> 1) & 3, rh = g & 1;
      long n = n0 + rh * 64 + lane;
      gld16(w1t + (long)p * 1048576L + n * 512 + kt * 32 + q * 8,
            &Bs[p][q][rh * 64][0]);
    }
    __syncthreads();
    float es[8];
    {
      f4 e0 = *(const f4*)&embS[kt * 32 + quad * 8];
      f4 e1 = *(const f4*)&embS[kt * 32 + quad * 8 + 4];
      es[0] = e0.x; es[1] = e0.y; es[2] = e0.z; es[3] = e0.w;
      es[4] = e1.x; es[5] = e1.y; es[6] = e1.z; es[7] = e1.w;
    }
    short8 af[3][4];
#pragma unroll
    for (int mt = 0; mt < 4; ++mt) {
      int row = wm + mt * 16 + ln15;
      f4 x0 = *(const f4*)&Au[quad][0][row][0];
      f4 x1 = *(const f4*)&Au[quad][1][row][0];
      float xs[8];
      xs[0] = x0.x + es[0]; xs[1] = x0.y + es[1];
      xs[2] = x0.z + es[2]; xs[3] = x0.w + es[3];
      xs[4] = x1.x + es[4]; xs[5] = x1.y + es[5];
      xs[6] = x1.z + es[6]; xs[7] = x1.w + es[7];
#pragma unroll
      for (int j = 0; j < 8; ++j) {
        unsigned short h_, m_, l_;
        split3(xs[j], h_, m_, l_);
        ((unsigned short*)&af[0][mt])[j] = h_;
        ((unsigned short*)&af[1][mt])[j] = m_;
        ((unsigned short*)&af[2][mt])[j] = l_;
      }
    }
#pragma unroll
    for (int pb = 0; pb < 3; ++pb) {
      short8 bfr[4];
#pragma unroll
      for (int nt = 0; nt < 4; ++nt)
        bfr[nt] = *(const short8*)&Bs[pb][quad][wn + nt * 16 + ln15][0];
      int npa = (pb == 0) ? 3 : ((pb == 1) ? 2 : 1);
      for (int pa = 0; pa < npa; ++pa)
#pragma unroll
        for (int mt = 0; mt < 4; ++mt)
#pragma unroll
          for (int nt = 0; nt < 4; ++nt)
            acc[mt][nt] = MFMA16(af[pa][mt], bfr[nt], acc[mt][nt], 0, 0, 0);
    }
  }
#pragma unroll
  for (int mt = 0; mt < 4; ++mt)
#pragma unroll
    for (int reg = 0; reg < 4; ++reg) {
      int r = m0 + wm + mt * 16 + quad * 4 + reg;
      if (r < mEnd) {
        long lr = r - c0;
#pragma unroll
        for (int nt = 0; nt < 4; ++nt) {
          int n = n0 + wn + nt * 16 + ln15;
          U[lr * 2048 + n] = fmaxf(acc[mt][nt][reg] + b1F[n], 0.f);
        }
      }
    }
}

// ---------- GEMM2: h = U*W2 + b2; state=h*mask; prev += h*uw; pdot8 -------
// A: U fp32 local rows; B: W2T planes; K=2048 (64 kt), N=512.
// Epilogue also writes deterministic per-strip partials of dot(h, Wp):
// pdot8[pos*8 + (n0>>7)*2 + (wv&1)] (8 fixed slots per row, no atomics).
__global__ __launch_bounds__(256) void k_gemm2(
    const float* __restrict__ U, const unsigned short* __restrict__ w2t,
    const float* __restrict__ b2F, const int* __restrict__ count,
    const int* __restrict__ ridx, const float* __restrict__ maskF,
    const float* __restrict__ uwF, const float* __restrict__ WpF,
    float* __restrict__ stateF, float* __restrict__ prevF,
    float* __restrict__ pdot8, int c0, int mc) {
  int Ma = *count;
  int mEnd = c0 + mc;
  if (Ma < mEnd) mEnd = Ma;
  int f = blockIdx.x;
  int x = f & 7, s = f >> 3;
  int n0 = (x >> 1) * 128;
  int m0 = c0 + (s * 2 + (x & 1)) * 128;
  if (m0 >= mEnd) return;
  __shared__ __align__(16) float Au[4][2][128][4];          // 16 KB fp32 A
  __shared__ __align__(16) unsigned short Bs[3][4][128][8]; // 24 KB B planes
  int tid = threadIdx.x;
  int lane = tid & 63, wv = tid >> 6;
  int quad = lane >> 4, ln15 = lane & 15;
  int wm = (wv >> 1) << 6, wn = (wv & 1) << 6;
  long lr0 = (long)(m0 - c0) + lane;
  long lr1 = lr0 + 64;
  f32x4 acc[4][4];
#pragma unroll
  for (int i = 0; i < 4; i++)
#pragma unroll
    for (int j = 0; j < 4; j++) acc[i][j] = (f32x4)0.f;
#pragma unroll 1
  for (int kt = 0; kt < 64; ++kt) {
    __syncthreads();
#pragma unroll
    for (int i = 0; i < 4; ++i) {  // A staging fp32
      int g = wv + 4 * i;
      int q = g >> 2, h = (g >> 1) & 1, rh = g & 1;
      long lr = rh ? lr1 : lr0;
      gld16(U + lr * 2048 + kt * 32 + q * 8 + h * 4, &Au[q][h][rh * 64][0]);
    }
#pragma unroll
    for (int i = 0; i < 6; ++i) {  // B staging
      int g = wv + 4 * i;
      int p = g >> 3, q = (g >> 1) & 3, rh = g & 1;
      long n = n0 + rh * 64 + lane;
      gld16(w2t + (long)p * 1048576L + n * 2048 + kt * 32 + q * 8,
            &Bs[p][q][rh * 64][0]);
    }
    __syncthreads();
    short8 af[3][4];
#pragma unroll
    for (int mt = 0; mt < 4; ++mt) {
      int row = wm + mt * 16 + ln15;
      f4 x0 = *(const f4*)&Au[quad][0][row][0];
      f4 x1 = *(const f4*)&Au[quad][1][row][0];
      float xs[8];
      xs[0] = x0.x; xs[1] = x0.y; xs[2] = x0.z; xs[3] = x0.w;
      xs[4] = x1.x; xs[5] = x1.y; xs[6] = x1.z; xs[7] = x1.w;
#pragma unroll
      for (int j = 0; j < 8; ++j) {
        unsigned short h_, m_, l_;
        split3(xs[j], h_, m_, l_);
        ((unsigned short*)&af[0][mt])[j] = h_;
        ((unsigned short*)&af[1][mt])[j] = m_;
        ((unsigned short*)&af[2][mt])[j] = l_;
      }
    }
#pragma unroll
    for (int pb = 0; pb < 3; ++pb) {
      short8 bfr[4];
#pragma unroll
      for (int nt = 0; nt < 4; ++nt)
        bfr[nt] = *(const short8*)&Bs[pb][quad][wn + nt * 16 + ln15][0];
      int npa = (pb == 0) ? 3 : ((pb == 1) ? 2 : 1);
      for (int pa = 0; pa < npa; ++pa)
#pragma unroll
        for (int mt = 0; mt < 4; ++mt)
#pragma unroll
          for (int nt = 0; nt < 4; ++nt)
            acc[mt][nt] = MFMA16(af[pa][mt], bfr[nt], acc[mt][nt], 0, 0, 0);
    }
  }
#pragma unroll
  for (int mt = 0; mt < 4; ++mt)
#pragma unroll
    for (int reg = 0; reg < 4; ++reg) {
      int r = m0 + wm + mt * 16 + quad * 4 + reg;
      // r is uniform across the 16 ln15 lanes of each quad-group, so the
      // shfl_xor reduction below is exec-uniform within its group.
      if (r < mEnd) {
        long pos = (long)ridx[r];
        float mk = maskF[pos];
        float uv = uwF[pos];
        float pd = 0.f;
#pragma unroll
        for (int nt = 0; nt < 4; ++nt) {
          int n = n0 + wn + nt * 16 + ln15;
          float h = (acc[mt][nt][reg] + b2F[n]) * mk;
          long off = pos * 512 + n;
          stateF[off] = h;
          prevF[off] = fmaf(h, uv, prevF[off]);
          pd = fmaf(h, WpF[n], pd);
        }
        pd += __shfl_xor(pd, 1, 64);
        pd += __shfl_xor(pd, 2, 64);
        pd += __shfl_xor(pd, 4, 64);
        pd += __shfl_xor(pd, 8, 64);
        if (ln15 == 0)
          pdot8[pos * 8 + (long)((n0 >> 7) * 2 + (wv & 1))] = pd;
      }
    }
}

// ---------- final: concat outputs, cast per detected dtype ----------
__global__ void k_final(const float* prevF, const float* nupF,
                        const float* remF, void* out, const void* mask) {
  int bf = detect_bf(mask);
  long gt = (long)blockIdx.x * 256 + threadIdx.x;
  long gs = (long)gridDim.x * 256;
  for (long i = gt; i < 8421376L; i += gs) {
    float v;
    if (i < 8388608L) v = prevF[i];
    else if (i < 8404992L) v = nupF[i - 8388608L];
    else v = remF[i - 8404992L];
    if (bf) ((__hip_bfloat16*)out)[i] = __float2bfloat16(v);
    else ((float*)out)[i] = v;
  }
}

extern "C" void kernel_launch(void* const* d_in, const int* in_sizes, int n_in,
                              void* d_out, int out_size, void* d_ws,
                              size_t ws_size, hipStream_t stream) {
  const void* state = d_in[0];
  const void* mask = d_in[1];
  const void* emb = d_in[2];
  const void* Wp = d_in[3];
  const void* bp = d_in[4];
  const void* W1 = d_in[5];
  const void* b1 = d_in[6];
  const void* W2 = d_in[7];
  const void* b2 = d_in[8];
  char* w = (char*)d_ws;
  float* stateF = (float*)(w + 0L);
  float* prevF = (float*)(w + 33554432L);
  unsigned short* w1t = (unsigned short*)(w + 67108864L);  // 3 x 2 MB
  unsigned short* w2t = (unsigned short*)(w + 73400320L);  // 3 x 2 MB
  float* maskF = (float*)(w + 79691776L);
  float* hp = (float*)(w + 79757312L);
  float* rem = (float*)(w + 79822848L);
  float* nup = (float*)(w + 79888384L);
  float* uwf = (float*)(w + 79953920L);
  float* embF = (float*)(w + 80019456L);
  float* WpF = (float*)(w + 80052224L);
  float* b1F = (float*)(w + 80056320L);
  float* b2F = (float*)(w + 80064512L);
  float* bpF = (float*)(w + 80068608L);
  int* counts = (int*)(w + 80069120L);    // 11 ints
  float* edot = (float*)(w + 80069632L);  // 11 floats
  int* ridx = (int*)(w + 80070144L);      // 11 x 16384 x 4 B
  float* pdot8 = (float*)(w + 80791040L); // 16384 x 8 fp32 = 512 KB
  float* U = (float*)(w + 81315328L);     // fp32 [Mc][2048]
  long ub = (long)ws_size - 81315328L;
  long rows = ub / 8192L;
  long McL = rows & ~255L;  // multiple of 256 so T=mc/128 stays even
  if (McL > 16384L) McL = 16384L;
  if (McL < 256L) McL = 256L;
  int Mc = (int)McL;
  int nCh = (16384 + Mc - 1) / Mc;

  k_prep<<<64, 256, 0, stream>>>(mask, emb, Wp, bp, b1, b2, embF, WpF, bpF,
                                 b1F, b2F, edot);
  k_init<<<2048, 256, 0, stream>>>(state, W1, W2, mask, Wp, stateF, w1t, w2t,
                                   maskF, prevF, hp, rem, nup, pdot8, counts);
  for (int t = 0; t <= 10; t++) {
    k_plite<<<64, 256, 0, stream>>>(pdot8, edot, bpF, hp, rem, nup, uwf,
                                    counts + t, ridx + (long)t * 16384, t);
    for (int c = 0; c < nCh; c++) {
      int c0 = c * Mc;
      int mc = 16384 - c0;
      if (mc > Mc) mc = Mc;
      int T = mc / 128;  // even (Mc multiple of 256, 16384 multiple of 256)
      k_gemm1<<<T * 16, 256, 0, stream>>>(stateF, embF + t * 512, w1t, b1F,
                                          counts + t, ridx + (long)t * 16384,
                                          U, c0, mc);
      k_gemm2<<<T * 4, 256, 0, stream>>>(U, w2t, b2F, counts + t,
                                         ridx + (long)t * 16384, maskF, uwf,
                                         WpF, stateF, prevF, pdot8, c0, mc);
    }
  }
  k_final<<<2048, 256, 0, stream>>>(prevF, nup, rem, d_out, mask);
}